// Round 7
// baseline (2422.138 us; speedup 1.0000x reference)
//
#include <hip/hip_runtime.h>
#include <cstdio>

// MoE top-2 FFN: B=4,S=2048,D=1024 -> T=8192 tokens; E=8, H=4096, K_TOP=2.
// Round 7: proven r2 GEMM loop (128x128, BK=32, 4 waves, 16KB LDS, gl16,
// 2 barriers/tile) + max TLP (__launch_bounds__(256,6) -> up to 6 blocks/CU)
// + n-fast XCD grid (A-panel L2 reuse) + T2 slot swizzle (validated r5)
// + non-temporal hbuf stores (stop L3 eviction of xg/W).

#define T_TOK 8192
#define DIM   1024
#define NEXP  8
#define HID   4096
#define MAXR  18432  // 16384 rows + 8 experts * up-to-255 pad, rounded to 256

typedef float          f32x4   __attribute__((ext_vector_type(4)));
typedef short          bf16x8  __attribute__((ext_vector_type(8)));
typedef unsigned short u16x4   __attribute__((ext_vector_type(4)));

static __device__ __forceinline__ unsigned short f2bf(float f) {
  unsigned int u = __builtin_bit_cast(unsigned int, f);
  u = (u + 0x7FFFu + ((u >> 16) & 1u)) >> 16;   // round-nearest-even (finite inputs)
  return (unsigned short)u;
}

// async global->LDS, 16B per lane; LDS dest = wave-uniform base + lane*16
static __device__ __forceinline__ void gl16(const void* g, void* l) {
  __builtin_amdgcn_global_load_lds(
      (const __attribute__((address_space(1))) unsigned int*)g,
      (__attribute__((address_space(3))) unsigned int*)l,
      16, 0, 0);
}

// ---------------- device bodies for the fused prep kernel --------------------
static __device__ __forceinline__ void transpose_body(const float* __restrict__ W,
                                                      unsigned short* __restrict__ WT,
                                                      int R, int C, int bx, int by, int e,
                                                      float (*tile)[33]) {
  int c0 = bx * 32, r0 = by * 32;
  const float* Wp = W + (size_t)e * R * C;
  unsigned short* Op = WT + (size_t)e * R * C;
  int tr = threadIdx.x >> 3;
  int tc = (threadIdx.x & 7) * 4;
  float4 v = *(const float4*)(Wp + (size_t)(r0 + tr) * C + c0 + tc);
  tile[tr][tc] = v.x; tile[tr][tc + 1] = v.y; tile[tr][tc + 2] = v.z; tile[tr][tc + 3] = v.w;
  __syncthreads();
  int oc  = threadIdx.x >> 3;
  int orr = (threadIdx.x & 7) * 4;
  u16x4 o;
#pragma unroll
  for (int j = 0; j < 4; ++j) o[j] = f2bf(tile[orr + j][oc]);
  *(u16x4*)(Op + (size_t)(c0 + oc) * R + r0 + orr) = o;
}

static __device__ __forceinline__ void router_body(int blk, const float* __restrict__ x,
                                                   const float* __restrict__ Wr,
                                                   const float* __restrict__ br,
                                                   int* __restrict__ meta,
                                                   int2* __restrict__ top_i,
                                                   float2* __restrict__ top_w) {
  int lane = threadIdx.x & 63;
  int wid  = threadIdx.x >> 6;
  int t = blk * 4 + wid;
  const float* xp = x + (size_t)t * DIM + lane * 16;
  float acc[NEXP];
#pragma unroll
  for (int e = 0; e < NEXP; ++e) acc[e] = 0.f;
#pragma unroll
  for (int j = 0; j < 16; j += 4) {
    float4 xv = *(const float4*)(xp + j);
    const float* wp = Wr + (size_t)(lane * 16 + j) * NEXP;
#pragma unroll
    for (int jj = 0; jj < 4; ++jj) {
      float xs = jj == 0 ? xv.x : jj == 1 ? xv.y : jj == 2 ? xv.z : xv.w;
      float4 w0 = *(const float4*)(wp + jj * NEXP);
      float4 w1 = *(const float4*)(wp + jj * NEXP + 4);
      acc[0] += xs * w0.x; acc[1] += xs * w0.y; acc[2] += xs * w0.z; acc[3] += xs * w0.w;
      acc[4] += xs * w1.x; acc[5] += xs * w1.y; acc[6] += xs * w1.z; acc[7] += xs * w1.w;
    }
  }
#pragma unroll
  for (int off = 32; off > 0; off >>= 1) {
#pragma unroll
    for (int e = 0; e < NEXP; ++e) acc[e] += __shfl_xor(acc[e], off);
  }
  if (lane == 0) {
    float l[NEXP];
#pragma unroll
    for (int e = 0; e < NEXP; ++e) l[e] = acc[e] + br[e];
    int e1 = 0;
#pragma unroll
    for (int e = 1; e < NEXP; ++e) if (l[e] > l[e1]) e1 = e;      // ties -> lower idx
    int e2 = (e1 == 0) ? 1 : 0;
#pragma unroll
    for (int e = 0; e < NEXP; ++e) if (e != e1 && l[e] > l[e2]) e2 = e;
    float g  = expf(l[e2] - l[e1]);              // softmax over top-2 == renorm of full softmax
    float w1 = 1.f / (1.f + g);
    top_i[t] = make_int2(e1, e2);
    top_w[t] = make_float2(w1, 1.f - w1);
    atomicAdd(&meta[e1], 1);
    atomicAdd(&meta[e2], 1);
  }
}

// ---- fused prep: [0,32768) W1 transpose, [32768,65536) W2 transpose,
//      [65536,67584) router, [67584,67656) fill pad-row arrays ---------------
__global__ __launch_bounds__(256) void prep_k(const float* __restrict__ W1,
                                              const float* __restrict__ W2,
                                              unsigned short* __restrict__ W1bT,
                                              unsigned short* __restrict__ W2bT,
                                              const float* __restrict__ x,
                                              const float* __restrict__ Wr,
                                              const float* __restrict__ br,
                                              int* __restrict__ meta,
                                              int2* __restrict__ top_i,
                                              float2* __restrict__ top_w,
                                              int* __restrict__ tok_of_row,
                                              float* __restrict__ wt_of_row) {
  __shared__ float tile[32][33];
  int id = blockIdx.x;
  if (id < 32768) {                              // W1[e][D][H] -> [e][H][D]
    transpose_body(W1, W1bT, DIM, HID, id & 127, (id >> 7) & 31, id >> 12, tile);
  } else if (id < 65536) {                       // W2[e][H][D] -> [e][D][H]
    int id2 = id - 32768;
    transpose_body(W2, W2bT, HID, DIM, id2 & 31, (id2 >> 5) & 127, id2 >> 12, tile);
  } else if (id < 67584) {
    router_body(id - 65536, x, Wr, br, meta, top_i, top_w);
  } else {
    int i = (id - 67584) * 256 + threadIdx.x;
    if (i < MAXR) { tok_of_row[i] = 0; wt_of_row[i] = 0.f; }
  }
}

// -------- prefix: padded (x256) offsets ------------------------------------
__global__ void prefix_k(int* __restrict__ meta) {
  if (threadIdx.x == 0) {
    int s = 0;
#pragma unroll
    for (int e = 0; e < NEXP; ++e) {
      meta[16 + e] = s;                          // poff[e]
      s += (meta[e] + 255) & ~255;
    }
    meta[24] = s;                                // poff[8]
    meta[25] = s;                                // total_padded (<= MAXR always)
  }
}

// ---------------- scatter: token -> packed expert row ------------------------
__global__ __launch_bounds__(256) void scatter_k(const int2* __restrict__ top_i,
                                                 const float2* __restrict__ top_w,
                                                 int* __restrict__ meta,
                                                 int* __restrict__ row_of,
                                                 int* __restrict__ tok_of_row,
                                                 float* __restrict__ wt_of_row) {
  int t = blockIdx.x * 256 + threadIdx.x;
  int2  ei = top_i[t];
  float2 w = top_w[t];
  int p = atomicAdd(&meta[8 + ei.x], 1);
  int r = meta[16 + ei.x] + p;
  tok_of_row[r] = t; wt_of_row[r] = w.x; row_of[t * 2] = r;
  p = atomicAdd(&meta[8 + ei.y], 1);
  r = meta[16 + ei.y] + p;
  tok_of_row[r] = t; wt_of_row[r] = w.y; row_of[t * 2 + 1] = r;
}

// ---------------- gather: xg[r][:] = bf16(x[tok[r]][:]) ----------------------
__global__ __launch_bounds__(256) void gather_k(const float* __restrict__ x,
                                                const int* __restrict__ tok_of_row,
                                                const int* __restrict__ meta,
                                                unsigned short* __restrict__ xg) {
  int r = blockIdx.x;
  if (r >= meta[25]) return;
  int t = tok_of_row[r];
  int c = threadIdx.x * 4;
  float4 v = *(const float4*)(x + (size_t)t * DIM + c);
  u16x4 o;
  o[0] = f2bf(v.x); o[1] = f2bf(v.y); o[2] = f2bf(v.z); o[3] = f2bf(v.w);
  *(u16x4*)(xg + (size_t)r * DIM + c) = o;
}

// ---------------- grouped GEMM: r2 loop + T2 swizzle + n-fast grid -----------
// A: [M][KTOT] bf16 packed rows.  Bt: [E][NTOT][KTOT] bf16 (pre-transposed).
// 128x128 tile, BK=32, 4 waves (2x2), 16KB LDS (A 0..4095, B 4096..8191 shorts).
// LDS region = [128 rows][4 slots x 8 shorts]; slot XOR-swizzled by (row>>1)&3
// (write via pre-swizzled global source col, read via XOR'd slot — r5-validated).
// Per K-tile: sync; 4x gl16; sync; 8x ds_read_b128; 16x mfma_16x16x32_bf16.
// EPI 0: h = bf16(gelu(acc+b1)) nontemporal   EPI 1: atomicAdd out[tok]+=..*wt

template <int KTOT, int NTOT, int EPI>
__global__ __launch_bounds__(256, 6) void gemmv7_k(const unsigned short* __restrict__ A,
                                                   const unsigned short* __restrict__ Bt,
                                                   const float* __restrict__ bias,
                                                   const int* __restrict__ meta,
                                                   const float* __restrict__ wt_of_row,
                                                   const int* __restrict__ tok_of_row,
                                                   void* __restrict__ Cout) {
  constexpr int NN  = NTOT / 128;                // 32 or 8
  constexpr int NXB = MAXR / 128;                // 144 row tiles
  constexpr int NWG = NXB * NN;                  // 4608 or 1152, both % 8 == 0
  constexpr int NKT = KTOT / 32;
  __shared__ __align__(16) unsigned short lds[8192];   // 16 KiB

  // XCD-chunked, n-fast within chunk: consecutive ids share row0 (A-panel hot)
  int id = ((int)blockIdx.x & 7) * (NWG / 8) + ((int)blockIdx.x >> 3);
  int n0   = (id % NN) * 128;
  int row0 = (id / NN) * 128;
  if (row0 >= meta[25]) return;                  // beyond padded total (block-uniform)
  int e = 0;
  while (meta[17 + e] <= row0) ++e;              // tiles never straddle experts
  const unsigned short* Bp = Bt + (size_t)e * NTOT * KTOT;

  int tid = threadIdx.x;
  int lane = tid & 63, wid = tid >> 6;
  int wm = wid >> 1, wn = wid & 1;               // 2x2 waves, each owns 64x64 of C

  // staging (T2 write side): granules tid (rows 0..63) and tid+256 (rows 64..127);
  // row = tid>>2, slot' = tid&3; source col-slot s = (tid&3) ^ ((tid>>3)&3)
  // ((row>>1)&3 identical for row and row+64)
  int s = (tid & 3) ^ ((tid >> 3) & 3);
  const unsigned short* pA0 = A + (size_t)(row0 + (tid >> 2)) * KTOT + s * 8;
  const unsigned short* pA1 = pA0 + (size_t)64 * KTOT;
  const unsigned short* pB0 = Bp + (size_t)(n0 + (tid >> 2)) * KTOT + s * 8;
  const unsigned short* pB1 = pB0 + (size_t)64 * KTOT;

  // fragment reads (T2 read side): row = w*64 + i*16 + am; slot = g ^ ((row>>1)&3)
  int am = lane & 15;
  int sF = ((lane >> 4) ^ ((lane >> 1) & 3)) * 8;
  int aoff = (wm * 64 + am) * 32 + sF;           // + i*512 per fragment
  int boff = 4096 + (wn * 64 + am) * 32 + sF;    // + j*512 per fragment

  f32x4 acc[4][4];
#pragma unroll
  for (int i = 0; i < 4; ++i)
#pragma unroll
    for (int j = 0; j < 4; ++j) acc[i][j] = (f32x4){0.f, 0.f, 0.f, 0.f};

  for (int kt = 0; kt < NKT; ++kt) {
    __syncthreads();                             // prev compute done before overwrite
    gl16(pA0 + kt * 32, lds + tid * 8);
    gl16(pA1 + kt * 32, lds + 2048 + tid * 8);
    gl16(pB0 + kt * 32, lds + 4096 + tid * 8);
    gl16(pB1 + kt * 32, lds + 6144 + tid * 8);
    __syncthreads();                             // compiler drains vmcnt before barrier
    bf16x8 af[4], bv[4];
#pragma unroll
    for (int i = 0; i < 4; ++i)
      af[i] = *(const bf16x8*)(lds + aoff + i * 512);
#pragma unroll
    for (int j = 0; j < 4; ++j)
      bv[j] = *(const bf16x8*)(lds + boff + j * 512);
#pragma unroll
    for (int i = 0; i < 4; ++i)
#pragma unroll
      for (int j = 0; j < 4; ++j)
        acc[i][j] = __builtin_amdgcn_mfma_f32_16x16x32_bf16(af[i], bv[j], acc[i][j], 0, 0, 0);
  }

  // epilogue.  C/D: col n = lane&15, row m = (lane>>4)*4 + reg  (validated)
  int rbase = row0 + wm * 64 + ((lane >> 4) << 2);
  int nbase = n0 + wn * 64 + am;
  if constexpr (EPI == 0) {
    unsigned short* Hp = (unsigned short*)Cout;
    const float* bp = bias + (size_t)e * NTOT;
#pragma unroll
    for (int i = 0; i < 4; ++i)
#pragma unroll
      for (int j = 0; j < 4; ++j) {
        int n = nbase + j * 16;
        float bv = bp[n];
#pragma unroll
        for (int g = 0; g < 4; ++g) {
          int m = rbase + i * 16 + g;
          float v = acc[i][j][g] + bv;
          v = 0.5f * v * (1.f + erff(v * 0.70710678118654752f));   // exact gelu
          __builtin_nontemporal_store(f2bf(v), Hp + (size_t)m * NTOT + n);
        }
      }
  } else {
    float* Op = (float*)Cout;
    const float* bp = bias + (size_t)e * NTOT;
#pragma unroll
    for (int i = 0; i < 4; ++i)
#pragma unroll
      for (int g = 0; g < 4; ++g) {
        int m = rbase + i * 16 + g;
        float wt = wt_of_row[m];
        if (wt != 0.f) {                         // pad rows excluded (wt exactly 0)
          float* orow = Op + (size_t)tok_of_row[m] * DIM;
#pragma unroll
          for (int j = 0; j < 4; ++j) {
            int n = nbase + j * 16;
            atomicAdd(orow + n, (acc[i][j][g] + bp[n]) * wt);
          }
        }
      }
  }
}

extern "C" void kernel_launch(void* const* d_in, const int* in_sizes, int n_in,
                              void* d_out, int out_size, void* d_ws, size_t ws_size,
                              hipStream_t stream) {
  const float* x  = (const float*)d_in[0];
  const float* Wr = (const float*)d_in[1];
  const float* br = (const float*)d_in[2];
  const float* W1 = (const float*)d_in[3];
  const float* b1 = (const float*)d_in[4];
  const float* W2 = (const float*)d_in[5];
  const float* b2 = (const float*)d_in[6];
  float* out = (float*)d_out;

  char* base = (char*)d_ws;
  size_t off = 0;
  auto carve = [&](size_t bytes) -> void* {
    void* r = base + off;
    off = (off + bytes + 255) & ~(size_t)255;
    return r;
  };
  int*            meta       = (int*)carve(26 * 4);
  int2*           top_i      = (int2*)carve((size_t)T_TOK * 8);
  float2*         top_w      = (float2*)carve((size_t)T_TOK * 8);
  int*            row_of     = (int*)carve((size_t)T_TOK * 2 * 4);
  int*            tok_of_row = (int*)carve((size_t)MAXR * 4);
  float*          wt_of_row  = (float*)carve((size_t)MAXR * 4);
  unsigned short* xg         = (unsigned short*)carve((size_t)MAXR * DIM * 2);
  unsigned short* W1bT       = (unsigned short*)carve((size_t)NEXP * DIM * HID * 2);
  unsigned short* W2bT       = (unsigned short*)carve((size_t)NEXP * DIM * HID * 2);
  unsigned short* hbuf       = (unsigned short*)carve((size_t)MAXR * HID * 2);
  if (off > ws_size) {
    fprintf(stderr, "kernel_launch: ws_size too small: need %zu have %zu\n", off, ws_size);
    return;
  }

  hipMemsetAsync(meta, 0, 26 * 4, stream);
  hipMemsetAsync(out, 0, (size_t)out_size * 4, stream);   // GEMM2 atomicAdds into out
  hipLaunchKernelGGL(prep_k, dim3(67656), dim3(256), 0, stream,
                     W1, W2, W1bT, W2bT, x, Wr, br, meta, top_i, top_w,
                     tok_of_row, wt_of_row);
  hipLaunchKernelGGL(prefix_k, dim3(1), dim3(64), 0, stream, meta);
  hipLaunchKernelGGL(scatter_k, dim3(T_TOK / 256), dim3(256), 0, stream,
                     top_i, top_w, meta, row_of, tok_of_row, wt_of_row);
  hipLaunchKernelGGL(gather_k, dim3(MAXR), dim3(256), 0, stream, x, tok_of_row, meta, xg);
  hipLaunchKernelGGL((gemmv7_k<DIM, HID, 0>), dim3((MAXR / 128) * (HID / 128)), dim3(256), 0,
                     stream, xg, W1bT, b1, meta, wt_of_row, tok_of_row, (void*)hbuf);
  hipLaunchKernelGGL((gemmv7_k<HID, DIM, 1>), dim3((MAXR / 128) * (DIM / 128)), dim3(256), 0,
                     stream, hbuf, W2bT, b2, meta, wt_of_row, tok_of_row, (void*)out);
}

// Round 8
// 867.992 us; speedup vs baseline: 2.7905x; 2.7905x over previous
//
#include <hip/hip_runtime.h>
#include <cstdio>

// MoE top-2 FFN: B=4,S=2048,D=1024 -> T=8192 tokens; E=8, H=4096, K_TOP=2.
// Round 8: r2's proven 2-barrier GEMM loop widened to BK=64 (2x MFMA per
// barrier pair), 32KB LDS, row-fast XCD grid (r2), plain stores (r7's NT
// stores and n-fast grid reverted), T2 8-slot XOR swizzle (r5-validated),
// 4 blocks/CU TLP. Prep fusion + atomic GEMM2 epilogue kept.

#define T_TOK 8192
#define DIM   1024
#define NEXP  8
#define HID   4096
#define MAXR  18432  // 16384 rows + 8 experts * up-to-255 pad, rounded to 256

typedef float          f32x4   __attribute__((ext_vector_type(4)));
typedef short          bf16x8  __attribute__((ext_vector_type(8)));
typedef unsigned short u16x4   __attribute__((ext_vector_type(4)));

static __device__ __forceinline__ unsigned short f2bf(float f) {
  unsigned int u = __builtin_bit_cast(unsigned int, f);
  u = (u + 0x7FFFu + ((u >> 16) & 1u)) >> 16;   // round-nearest-even (finite inputs)
  return (unsigned short)u;
}

// async global->LDS, 16B per lane; LDS dest = wave-uniform base + lane*16
static __device__ __forceinline__ void gl16(const void* g, void* l) {
  __builtin_amdgcn_global_load_lds(
      (const __attribute__((address_space(1))) unsigned int*)g,
      (__attribute__((address_space(3))) unsigned int*)l,
      16, 0, 0);
}

// ---------------- device bodies for the fused prep kernel --------------------
static __device__ __forceinline__ void transpose_body(const float* __restrict__ W,
                                                      unsigned short* __restrict__ WT,
                                                      int R, int C, int bx, int by, int e,
                                                      float (*tile)[33]) {
  int c0 = bx * 32, r0 = by * 32;
  const float* Wp = W + (size_t)e * R * C;
  unsigned short* Op = WT + (size_t)e * R * C;
  int tr = threadIdx.x >> 3;
  int tc = (threadIdx.x & 7) * 4;
  float4 v = *(const float4*)(Wp + (size_t)(r0 + tr) * C + c0 + tc);
  tile[tr][tc] = v.x; tile[tr][tc + 1] = v.y; tile[tr][tc + 2] = v.z; tile[tr][tc + 3] = v.w;
  __syncthreads();
  int oc  = threadIdx.x >> 3;
  int orr = (threadIdx.x & 7) * 4;
  u16x4 o;
#pragma unroll
  for (int j = 0; j < 4; ++j) o[j] = f2bf(tile[orr + j][oc]);
  *(u16x4*)(Op + (size_t)(c0 + oc) * R + r0 + orr) = o;
}

static __device__ __forceinline__ void router_body(int blk, const float* __restrict__ x,
                                                   const float* __restrict__ Wr,
                                                   const float* __restrict__ br,
                                                   int* __restrict__ meta,
                                                   int2* __restrict__ top_i,
                                                   float2* __restrict__ top_w) {
  int lane = threadIdx.x & 63;
  int wid  = threadIdx.x >> 6;
  int t = blk * 4 + wid;
  const float* xp = x + (size_t)t * DIM + lane * 16;
  float acc[NEXP];
#pragma unroll
  for (int e = 0; e < NEXP; ++e) acc[e] = 0.f;
#pragma unroll
  for (int j = 0; j < 16; j += 4) {
    float4 xv = *(const float4*)(xp + j);
    const float* wp = Wr + (size_t)(lane * 16 + j) * NEXP;
#pragma unroll
    for (int jj = 0; jj < 4; ++jj) {
      float xs = jj == 0 ? xv.x : jj == 1 ? xv.y : jj == 2 ? xv.z : xv.w;
      float4 w0 = *(const float4*)(wp + jj * NEXP);
      float4 w1 = *(const float4*)(wp + jj * NEXP + 4);
      acc[0] += xs * w0.x; acc[1] += xs * w0.y; acc[2] += xs * w0.z; acc[3] += xs * w0.w;
      acc[4] += xs * w1.x; acc[5] += xs * w1.y; acc[6] += xs * w1.z; acc[7] += xs * w1.w;
    }
  }
#pragma unroll
  for (int off = 32; off > 0; off >>= 1) {
#pragma unroll
    for (int e = 0; e < NEXP; ++e) acc[e] += __shfl_xor(acc[e], off);
  }
  if (lane == 0) {
    float l[NEXP];
#pragma unroll
    for (int e = 0; e < NEXP; ++e) l[e] = acc[e] + br[e];
    int e1 = 0;
#pragma unroll
    for (int e = 1; e < NEXP; ++e) if (l[e] > l[e1]) e1 = e;      // ties -> lower idx
    int e2 = (e1 == 0) ? 1 : 0;
#pragma unroll
    for (int e = 0; e < NEXP; ++e) if (e != e1 && l[e] > l[e2]) e2 = e;
    float g  = expf(l[e2] - l[e1]);              // softmax over top-2 == renorm of full softmax
    float w1 = 1.f / (1.f + g);
    top_i[t] = make_int2(e1, e2);
    top_w[t] = make_float2(w1, 1.f - w1);
    atomicAdd(&meta[e1], 1);
    atomicAdd(&meta[e2], 1);
  }
}

// ---- fused prep: [0,32768) W1 transpose, [32768,65536) W2 transpose,
//      [65536,67584) router, [67584,67656) fill pad-row arrays ---------------
__global__ __launch_bounds__(256) void prep_k(const float* __restrict__ W1,
                                              const float* __restrict__ W2,
                                              unsigned short* __restrict__ W1bT,
                                              unsigned short* __restrict__ W2bT,
                                              const float* __restrict__ x,
                                              const float* __restrict__ Wr,
                                              const float* __restrict__ br,
                                              int* __restrict__ meta,
                                              int2* __restrict__ top_i,
                                              float2* __restrict__ top_w,
                                              int* __restrict__ tok_of_row,
                                              float* __restrict__ wt_of_row) {
  __shared__ float tile[32][33];
  int id = blockIdx.x;
  if (id < 32768) {                              // W1[e][D][H] -> [e][H][D]
    transpose_body(W1, W1bT, DIM, HID, id & 127, (id >> 7) & 31, id >> 12, tile);
  } else if (id < 65536) {                       // W2[e][H][D] -> [e][D][H]
    int id2 = id - 32768;
    transpose_body(W2, W2bT, HID, DIM, id2 & 31, (id2 >> 5) & 127, id2 >> 12, tile);
  } else if (id < 67584) {
    router_body(id - 65536, x, Wr, br, meta, top_i, top_w);
  } else {
    int i = (id - 67584) * 256 + threadIdx.x;
    if (i < MAXR) { tok_of_row[i] = 0; wt_of_row[i] = 0.f; }
  }
}

// -------- prefix: padded (x256) offsets ------------------------------------
__global__ void prefix_k(int* __restrict__ meta) {
  if (threadIdx.x == 0) {
    int s = 0;
#pragma unroll
    for (int e = 0; e < NEXP; ++e) {
      meta[16 + e] = s;                          // poff[e]
      s += (meta[e] + 255) & ~255;
    }
    meta[24] = s;                                // poff[8]
    meta[25] = s;                                // total_padded (<= MAXR always)
  }
}

// ---------------- scatter: token -> packed expert row ------------------------
__global__ __launch_bounds__(256) void scatter_k(const int2* __restrict__ top_i,
                                                 const float2* __restrict__ top_w,
                                                 int* __restrict__ meta,
                                                 int* __restrict__ row_of,
                                                 int* __restrict__ tok_of_row,
                                                 float* __restrict__ wt_of_row) {
  int t = blockIdx.x * 256 + threadIdx.x;
  int2  ei = top_i[t];
  float2 w = top_w[t];
  int p = atomicAdd(&meta[8 + ei.x], 1);
  int r = meta[16 + ei.x] + p;
  tok_of_row[r] = t; wt_of_row[r] = w.x; row_of[t * 2] = r;
  p = atomicAdd(&meta[8 + ei.y], 1);
  r = meta[16 + ei.y] + p;
  tok_of_row[r] = t; wt_of_row[r] = w.y; row_of[t * 2 + 1] = r;
}

// ---------------- gather: xg[r][:] = bf16(x[tok[r]][:]) ----------------------
__global__ __launch_bounds__(256) void gather_k(const float* __restrict__ x,
                                                const int* __restrict__ tok_of_row,
                                                const int* __restrict__ meta,
                                                unsigned short* __restrict__ xg) {
  int r = blockIdx.x;
  if (r >= meta[25]) return;
  int t = tok_of_row[r];
  int c = threadIdx.x * 4;
  float4 v = *(const float4*)(x + (size_t)t * DIM + c);
  u16x4 o;
  o[0] = f2bf(v.x); o[1] = f2bf(v.y); o[2] = f2bf(v.z); o[3] = f2bf(v.w);
  *(u16x4*)(xg + (size_t)r * DIM + c) = o;
}

// ---------------- grouped GEMM: r2 loop, BK=64, T2 swizzle -------------------
// A: [M][KTOT] bf16 packed rows.  Bt: [E][NTOT][KTOT] bf16 (pre-transposed).
// 128x128 tile, BK=64, 4 waves (2x2), 32KB LDS (A shorts [0,8192), B [8192,16384)).
// LDS region = [128 rows][8 slots x 8 shorts], row stride 128B; slot
// XOR-swizzled by row&7 (write: pre-swizzled global source col; read: XOR slot).
// Per K-tile: sync; 8x gl16; sync; 2 k-steps x {8x ds_read_b128, 16x MFMA}.
// EPI 0: h = bf16(gelu(acc+b1)) plain store   EPI 1: atomicAdd out[tok]+=..*wt

template <int KTOT, int NTOT, int EPI>
__global__ __launch_bounds__(256, 4) void gemmv8_k(const unsigned short* __restrict__ A,
                                                   const unsigned short* __restrict__ Bt,
                                                   const float* __restrict__ bias,
                                                   const int* __restrict__ meta,
                                                   const float* __restrict__ wt_of_row,
                                                   const int* __restrict__ tok_of_row,
                                                   void* __restrict__ Cout) {
  constexpr int NN  = NTOT / 128;                // 32 or 8
  constexpr int NXB = MAXR / 128;                // 144 row tiles
  constexpr int NWG = NXB * NN;                  // 4608 or 1152, both % 8 == 0
  constexpr int NKT = KTOT / 64;                 // 16 or 64
  __shared__ __align__(16) unsigned short lds[16384];   // 32 KiB

  // XCD-chunked, ROW-fast within chunk (r2-proven): consecutive ids share n0
  int id = ((int)blockIdx.x & 7) * (NWG / 8) + ((int)blockIdx.x >> 3);
  int row0 = (id % NXB) * 128;
  int n0   = (id / NXB) * 128;
  if (row0 >= meta[25]) return;                  // beyond padded total (block-uniform)
  int e = 0;
  while (meta[17 + e] <= row0) ++e;              // tiles never straddle experts
  const unsigned short* Bp = Bt + (size_t)e * NTOT * KTOT;

  int tid = threadIdx.x;
  int lane = tid & 63, wid = tid >> 6;
  int wm = wid >> 1, wn = wid & 1;               // 2x2 waves, each owns 64x64 of C

  // staging (T2 write side): issue i covers granules i*256+tid ->
  // row = i*32 + (tid>>3), slot' = tid&7; row&7 = (tid>>3)&7 for all i,
  // so source col-slot s = (tid&7) ^ ((tid>>3)&7) is issue-invariant.
  int s = (tid & 7) ^ ((tid >> 3) & 7);
  const unsigned short* pA = A  + (size_t)(row0 + (tid >> 3)) * KTOT + s * 8;
  const unsigned short* pB = Bp + (size_t)(n0   + (tid >> 3)) * KTOT + s * 8;

  // fragment reads (T2 read side): row = w*64 + i*16 + am; row&7 = am&7;
  // k-step kk, k-group g=lane>>4 -> slot = (kk*4+g) ^ (am&7)
  int am = lane & 15, g = lane >> 4;
  int sw0 = ((0 * 4 + g) ^ (am & 7)) * 8;
  int sw1 = ((1 * 4 + g) ^ (am & 7)) * 8;
  int aRow = (wm * 64 + am) * 64;                // + i*1024 per fragment
  int bRow = 8192 + (wn * 64 + am) * 64;         // + j*1024 per fragment

  f32x4 acc[4][4];
#pragma unroll
  for (int i = 0; i < 4; ++i)
#pragma unroll
    for (int j = 0; j < 4; ++j) acc[i][j] = (f32x4){0.f, 0.f, 0.f, 0.f};

  for (int kt = 0; kt < NKT; ++kt) {
    __syncthreads();                             // prev compute done before overwrite
#pragma unroll
    for (int i = 0; i < 4; ++i) {                // A: rows i*32..i*32+31
      gl16(pA + (size_t)(i * 32) * KTOT + kt * 64, lds + i * 2048 + tid * 8);
      gl16(pB + (size_t)(i * 32) * KTOT + kt * 64, lds + 8192 + i * 2048 + tid * 8);
    }
    __syncthreads();                             // compiler drains vmcnt before barrier
#pragma unroll
    for (int kk = 0; kk < 2; ++kk) {
      int sw = kk ? sw1 : sw0;
      bf16x8 af[4], bv[4];
#pragma unroll
      for (int i = 0; i < 4; ++i)
        af[i] = *(const bf16x8*)(lds + aRow + i * 1024 + sw);
#pragma unroll
      for (int j = 0; j < 4; ++j)
        bv[j] = *(const bf16x8*)(lds + bRow + j * 1024 + sw);
#pragma unroll
      for (int i = 0; i < 4; ++i)
#pragma unroll
        for (int j = 0; j < 4; ++j)
          acc[i][j] = __builtin_amdgcn_mfma_f32_16x16x32_bf16(af[i], bv[j], acc[i][j], 0, 0, 0);
    }
  }

  // epilogue.  C/D: col n = lane&15, row m = (lane>>4)*4 + reg  (validated)
  int rbase = row0 + wm * 64 + (g << 2);
  int nbase = n0 + wn * 64 + am;
  if constexpr (EPI == 0) {
    unsigned short* Hp = (unsigned short*)Cout;
    const float* bp = bias + (size_t)e * NTOT;
#pragma unroll
    for (int i = 0; i < 4; ++i)
#pragma unroll
      for (int j = 0; j < 4; ++j) {
        int n = nbase + j * 16;
        float bv = bp[n];
#pragma unroll
        for (int gg = 0; gg < 4; ++gg) {
          int m = rbase + i * 16 + gg;
          float v = acc[i][j][gg] + bv;
          v = 0.5f * v * (1.f + erff(v * 0.70710678118654752f));   // exact gelu
          Hp[(size_t)m * NTOT + n] = f2bf(v);
        }
      }
  } else {
    float* Op = (float*)Cout;
    const float* bp = bias + (size_t)e * NTOT;
#pragma unroll
    for (int i = 0; i < 4; ++i)
#pragma unroll
      for (int gg = 0; gg < 4; ++gg) {
        int m = rbase + i * 16 + gg;
        float wt = wt_of_row[m];
        if (wt != 0.f) {                         // pad rows excluded (wt exactly 0)
          float* orow = Op + (size_t)tok_of_row[m] * DIM;
#pragma unroll
          for (int j = 0; j < 4; ++j) {
            int n = nbase + j * 16;
            atomicAdd(orow + n, (acc[i][j][gg] + bp[n]) * wt);
          }
        }
      }
  }
}

extern "C" void kernel_launch(void* const* d_in, const int* in_sizes, int n_in,
                              void* d_out, int out_size, void* d_ws, size_t ws_size,
                              hipStream_t stream) {
  const float* x  = (const float*)d_in[0];
  const float* Wr = (const float*)d_in[1];
  const float* br = (const float*)d_in[2];
  const float* W1 = (const float*)d_in[3];
  const float* b1 = (const float*)d_in[4];
  const float* W2 = (const float*)d_in[5];
  const float* b2 = (const float*)d_in[6];
  float* out = (float*)d_out;

  char* base = (char*)d_ws;
  size_t off = 0;
  auto carve = [&](size_t bytes) -> void* {
    void* r = base + off;
    off = (off + bytes + 255) & ~(size_t)255;
    return r;
  };
  int*            meta       = (int*)carve(26 * 4);
  int2*           top_i      = (int2*)carve((size_t)T_TOK * 8);
  float2*         top_w      = (float2*)carve((size_t)T_TOK * 8);
  int*            row_of     = (int*)carve((size_t)T_TOK * 2 * 4);
  int*            tok_of_row = (int*)carve((size_t)MAXR * 4);
  float*          wt_of_row  = (float*)carve((size_t)MAXR * 4);
  unsigned short* xg         = (unsigned short*)carve((size_t)MAXR * DIM * 2);
  unsigned short* W1bT       = (unsigned short*)carve((size_t)NEXP * DIM * HID * 2);
  unsigned short* W2bT       = (unsigned short*)carve((size_t)NEXP * DIM * HID * 2);
  unsigned short* hbuf       = (unsigned short*)carve((size_t)MAXR * HID * 2);
  if (off > ws_size) {
    fprintf(stderr, "kernel_launch: ws_size too small: need %zu have %zu\n", off, ws_size);
    return;
  }

  hipMemsetAsync(meta, 0, 26 * 4, stream);
  hipMemsetAsync(out, 0, (size_t)out_size * 4, stream);   // GEMM2 atomicAdds into out
  hipLaunchKernelGGL(prep_k, dim3(67656), dim3(256), 0, stream,
                     W1, W2, W1bT, W2bT, x, Wr, br, meta, top_i, top_w,
                     tok_of_row, wt_of_row);
  hipLaunchKernelGGL(prefix_k, dim3(1), dim3(64), 0, stream, meta);
  hipLaunchKernelGGL(scatter_k, dim3(T_TOK / 256), dim3(256), 0, stream,
                     top_i, top_w, meta, row_of, tok_of_row, wt_of_row);
  hipLaunchKernelGGL(gather_k, dim3(MAXR), dim3(256), 0, stream, x, tok_of_row, meta, xg);
  hipLaunchKernelGGL((gemmv8_k<DIM, HID, 0>), dim3((MAXR / 128) * (HID / 128)), dim3(256), 0,
                     stream, xg, W1bT, b1, meta, wt_of_row, tok_of_row, (void*)hbuf);
  hipLaunchKernelGGL((gemmv8_k<HID, DIM, 1>), dim3((MAXR / 128) * (DIM / 128)), dim3(256), 0,
                     stream, hbuf, W2bT, b2, meta, wt_of_row, tok_of_row, (void*)out);
}